// Round 5
// baseline (224.808 us; speedup 1.0000x reference)
//
#include <hip/hip_runtime.h>

#define ROWS_PER_TILE 64
#define THREADS 64
#define ROW_F 85        // floats per row
#define NCLS 80         // classes
#define CONF_THRESH 0.25f

#define TILE_F (ROWS_PER_TILE * ROW_F)   // 5440 floats = 21,760 B LDS
#define TILE_V (TILE_F / 4)              // 1360 float4
#define PER_THREAD 21                    // 64*21 = 1344
#define TAIL_V (TILE_V - PER_THREAD * THREADS)  // 16
#define TILES_PER_BLOCK 4

// Single wave (64 threads) per block, 21,760 B LDS -> 7 blocks/CU. Each block
// processes 4 consecutive 64-row tiles, software-pipelined: while computing
// tile i from LDS, tile i+1's 22 float4 loads are in flight in registers;
// after compute, regs -> LDS. NO __syncthreads (single wave; a barrier's
// vmcnt(0) drain would serialize the prefetch). In-wave correctness comes
// from the in-order per-wave DS pipe.
//
// __launch_bounds__(64, 1): CRITICAL. The prefetch buffer (22 float4 = 88
// VGPRs) must stay live across the whole compute phase. Without the "min 1
// wave/EU" hint the allocator capped at 100 VGPRs and spilled the buffer to
// scratch (R4: WRITE_SIZE 9.45 -> 132 MB, VALUBusy ~0%). With it, up to ~512
// VGPRs are allowed; occupancy stays LDS-limited at 7 blocks/CU regardless.
//
// LDS row stride 85: t*85 % 32 = t*21 % 32 is a bank permutation (21 odd) ->
// compute-phase reads conflict-free.
__global__ __launch_bounds__(THREADS, 1) void yolo_post_kernel(
    const float* __restrict__ in, float* __restrict__ out, long long nrows) {
  __shared__ float tile[TILE_F];
  float4* dstv = (float4*)tile;
  const int t = threadIdx.x;

  const long long full_tiles = nrows / ROWS_PER_TILE;
  const long long ntiles = (nrows + ROWS_PER_TILE - 1) / ROWS_PER_TILE;
  long long ti = (long long)blockIdx.x * TILES_PER_BLOCK;
  long long ti_end = ti + TILES_PER_BLOCK;
  if (ti_end > ntiles) ti_end = ntiles;
  if (ti >= ti_end) return;
  long long full_end = ti_end < full_tiles ? ti_end : full_tiles;

  float4 v[PER_THREAD];
  float4 extra;

  // ---------------- pipelined path over FULL tiles ----------------
  if (ti < full_end) {
    // prologue: load tile ti into regs, then regs -> LDS
    {
      const float4* __restrict__ src = (const float4*)(in + ti * TILE_F);
#pragma unroll
      for (int k = 0; k < PER_THREAD; ++k) v[k] = src[t + k * THREADS];
      if (t < TAIL_V) extra = src[PER_THREAD * THREADS + t];
    }
#pragma unroll
    for (int k = 0; k < PER_THREAD; ++k) dstv[t + k * THREADS] = v[k];
    if (t < TAIL_V) dstv[PER_THREAD * THREADS + t] = extra;

    while (ti < full_end) {
      const long long nxt = ti + 1;
      const bool have_next = nxt < full_end;
      if (have_next) {
        // prefetch next tile into regs; loads stay in flight during compute
        const float4* __restrict__ src = (const float4*)(in + nxt * TILE_F);
#pragma unroll
        for (int k = 0; k < PER_THREAD; ++k) v[k] = src[t + k * THREADS];
        if (t < TAIL_V) extra = src[PER_THREAD * THREADS + t];
      }

      // ---- compute current tile from LDS ----
      const long long r = ti * ROWS_PER_TILE + t;
      const float* row = tile + t * ROW_F;
      float cx = row[0];
      float cy = row[1];
      float hw = row[2] * 0.5f;
      float hh = row[3] * 0.5f;
      float conf = row[4];
      float best = row[5];
      int bidx = 0;
#pragma unroll
      for (int c = 1; c < NCLS; ++c) {
        float x = row[5 + c];
        bool g = x > best;           // strict > keeps FIRST max (jnp.argmax)
        best = g ? x : best;
        bidx = g ? c : bidx;
      }
      float score = conf * best;
      bool keep = score > CONF_THRESH;
      float2 o01 = keep ? make_float2(cx - hw, cy - hh) : make_float2(0.f, 0.f);
      float2 o23 = keep ? make_float2(cx + hw, cy + hh) : make_float2(0.f, 0.f);
      float2 o45 = keep ? make_float2(score, (float)bidx) : make_float2(0.f, 0.f);
      float2* op = (float2*)(out + r * 6);   // r*24 B, 8 B aligned
      op[0] = o01;
      op[1] = o23;
      op[2] = o45;

      if (have_next) {
        // drain prefetch into LDS (in-order DS pipe: after the reads above)
#pragma unroll
        for (int k = 0; k < PER_THREAD; ++k) dstv[t + k * THREADS] = v[k];
        if (t < TAIL_V) dstv[PER_THREAD * THREADS + t] = extra;
      }
      ti = nxt;
    }
  }

  // ---------------- guarded path for the (at most one) partial tile ----------------
  if (ti < ti_end) {   // ti == full_tiles, partial tile exists
    const long long r = ti * ROWS_PER_TILE + t;
    if (r < nrows) {
      const float* __restrict__ row = in + r * ROW_F;  // direct global, tiny tail
      float cx = row[0];
      float cy = row[1];
      float hw = row[2] * 0.5f;
      float hh = row[3] * 0.5f;
      float conf = row[4];
      float best = row[5];
      int bidx = 0;
      for (int c = 1; c < NCLS; ++c) {
        float x = row[5 + c];
        bool g = x > best;
        best = g ? x : best;
        bidx = g ? c : bidx;
      }
      float score = conf * best;
      bool keep = score > CONF_THRESH;
      float* op = out + r * 6;
      op[0] = keep ? cx - hw : 0.0f;
      op[1] = keep ? cy - hh : 0.0f;
      op[2] = keep ? cx + hw : 0.0f;
      op[3] = keep ? cy + hh : 0.0f;
      op[4] = keep ? score : 0.0f;
      op[5] = keep ? (float)bidx : 0.0f;
    }
  }
}

extern "C" void kernel_launch(void* const* d_in, const int* in_sizes, int n_in,
                              void* d_out, int out_size, void* d_ws, size_t ws_size,
                              hipStream_t stream) {
  const float* in = (const float*)d_in[0];
  float* out = (float*)d_out;
  const long long nrows = (long long)in_sizes[0] / ROW_F;            // 403200
  const long long ntiles = (nrows + ROWS_PER_TILE - 1) / ROWS_PER_TILE;  // 6300
  const int grid = (int)((ntiles + TILES_PER_BLOCK - 1) / TILES_PER_BLOCK);  // 1575
  yolo_post_kernel<<<grid, THREADS, 0, stream>>>(in, out, nrows);
}

// Round 6
// 206.845 us; speedup vs baseline: 1.0868x; 1.0868x over previous
//
#include <hip/hip_runtime.h>

#define ROWS_PER_TILE 64
#define THREADS 64
#define ROW_F 85        // floats per row
#define NCLS 80         // classes
#define CONF_THRESH 0.25f

#define TILE_F (ROWS_PER_TILE * ROW_F)   // 5440 floats = 21,760 B per buffer
#define TILE_V (TILE_F / 4)              // 1360 float4
#define PER_THREAD 21                    // 64*21 = 1344 vec4; +16 tail vec4
#define TAIL_V (TILE_V - PER_THREAD * THREADS)  // 16
#define TILES_PER_BLOCK 8

#define GLOBAL_AS __attribute__((address_space(1)))
#define LDS_AS __attribute__((address_space(3)))

// Single-wave blocks, double-buffered LDS (2 x 21,760 B -> 3 blocks/CU), each
// block walks 8 consecutive 64-row tiles. Staging uses
// __builtin_amdgcn_global_load_lds width=16: direct global->LDS DMA with ZERO
// VGPR footprint (R4/R5 showed any in-register prefetch buffer gets demoted
// to scratch: 130+ MB of spill traffic, VGPR stuck at 100). Our pattern is
// exactly the instruction's required shape: wave-uniform LDS base + lane*16,
// lane-contiguous global addresses.
//
// Pipeline order per iteration: __syncthreads() drains the PREVIOUS tile's
// prefetch (1-wave block -> barrier is just a waitcnt), THEN issue the next
// tile's 22 async loads, THEN compute the current buffer. The barrier's
// vmcnt(0) drain therefore never covers the prefetch just issued — load
// latency hides under the ~1300-cycle compute phase.
//
// LDS row stride 85: bank(t*85 + j) = (t*21 + j) % 32 is a permutation in t
// (21 odd) -> the 85 scalar compute reads are conflict-free (2 lanes/bank is
// free per m136).
__global__ __launch_bounds__(THREADS) void yolo_post_kernel(
    const float* __restrict__ in, float* __restrict__ out, long long nrows) {
  __shared__ float tile[2][TILE_F];
  const int t = threadIdx.x;

  const long long full_tiles = nrows / ROWS_PER_TILE;
  const long long ntiles = (nrows + ROWS_PER_TILE - 1) / ROWS_PER_TILE;
  long long ti = (long long)blockIdx.x * TILES_PER_BLOCK;
  long long ti_end = ti + TILES_PER_BLOCK;
  if (ti_end > ntiles) ti_end = ntiles;
  if (ti >= ti_end) return;
  long long full_end = ti_end < full_tiles ? ti_end : full_tiles;

  // --- async stage of one full tile into buffer b: zero VGPR cost ---
  auto stage = [&](int b, long long tt) {
    const float* src = in + tt * TILE_F;   // tile-contiguous global
#pragma unroll
    for (int k = 0; k < PER_THREAD; ++k) {
      // lane's 16B: global (t + k*64)*16 from tile base; LDS base k*1024 (uniform)
      __builtin_amdgcn_global_load_lds(
          (const GLOBAL_AS void*)(src + (long long)(t + k * THREADS) * 4),
          (LDS_AS void*)(&tile[b][k * THREADS * 4]), 16, 0, 0);
    }
    if (t < TAIL_V) {
      __builtin_amdgcn_global_load_lds(
          (const GLOBAL_AS void*)(src + (long long)(t + PER_THREAD * THREADS) * 4),
          (LDS_AS void*)(&tile[b][PER_THREAD * THREADS * 4]), 16, 0, 0);
    }
  };

  if (ti < full_end) {
    int cur = 0;
    stage(0, ti);                      // prologue prefetch
    for (; ti < full_end; ++ti) {
      __syncthreads();                 // drain prev prefetch -> tile[cur] ready
      if (ti + 1 < full_end) stage(cur ^ 1, ti + 1);  // issue AFTER the wait

      // ---- compute tile[cur]: one lane per row ----
      const long long r = ti * ROWS_PER_TILE + t;
      const float* row = &tile[cur][t * ROW_F];
      float cx = row[0];
      float cy = row[1];
      float hw = row[2] * 0.5f;
      float hh = row[3] * 0.5f;
      float conf = row[4];
      float best = row[5];
      int bidx = 0;
#pragma unroll
      for (int c = 1; c < NCLS; ++c) {
        float x = row[5 + c];
        bool g = x > best;             // strict > keeps FIRST max (jnp.argmax)
        best = g ? x : best;
        bidx = g ? c : bidx;
      }
      float score = conf * best;
      bool keep = score > CONF_THRESH;
      float2 o01 = keep ? make_float2(cx - hw, cy - hh) : make_float2(0.f, 0.f);
      float2 o23 = keep ? make_float2(cx + hw, cy + hh) : make_float2(0.f, 0.f);
      float2 o45 = keep ? make_float2(score, (float)bidx) : make_float2(0.f, 0.f);
      float2* op = (float2*)(out + r * 6);   // r*24 B, 8 B aligned
      op[0] = o01;
      op[1] = o23;
      op[2] = o45;

      cur ^= 1;
    }
  }

  // ---- guarded path for the (at most one) partial tile ----
  if (ti < ti_end) {                   // ti == full_tiles
    const long long r = ti * ROWS_PER_TILE + t;
    if (r < nrows) {
      const float* __restrict__ row = in + r * ROW_F;  // direct global, tiny tail
      float cx = row[0];
      float cy = row[1];
      float hw = row[2] * 0.5f;
      float hh = row[3] * 0.5f;
      float conf = row[4];
      float best = row[5];
      int bidx = 0;
      for (int c = 1; c < NCLS; ++c) {
        float x = row[5 + c];
        bool g = x > best;
        best = g ? x : best;
        bidx = g ? c : bidx;
      }
      float score = conf * best;
      bool keep = score > CONF_THRESH;
      float* op = out + r * 6;
      op[0] = keep ? cx - hw : 0.0f;
      op[1] = keep ? cy - hh : 0.0f;
      op[2] = keep ? cx + hw : 0.0f;
      op[3] = keep ? cy + hh : 0.0f;
      op[4] = keep ? score : 0.0f;
      op[5] = keep ? (float)bidx : 0.0f;
    }
  }
}

extern "C" void kernel_launch(void* const* d_in, const int* in_sizes, int n_in,
                              void* d_out, int out_size, void* d_ws, size_t ws_size,
                              hipStream_t stream) {
  const float* in = (const float*)d_in[0];
  float* out = (float*)d_out;
  const long long nrows = (long long)in_sizes[0] / ROW_F;                 // 403200
  const long long ntiles = (nrows + ROWS_PER_TILE - 1) / ROWS_PER_TILE;   // 6300
  const int grid = (int)((ntiles + TILES_PER_BLOCK - 1) / TILES_PER_BLOCK);  // 788
  yolo_post_kernel<<<grid, THREADS, 0, stream>>>(in, out, nrows);
}

// Round 7
// 194.911 us; speedup vs baseline: 1.1534x; 1.0612x over previous
//
#include <hip/hip_runtime.h>

#define ROWS_PER_TILE 64
#define ROW_F 85                       // floats per row
#define NCLS 80
#define CONF_THRESH 0.25f
#define TILE_F (ROWS_PER_TILE * ROW_F) // 5440 floats = 21,760 B per buffer
#define NBUF 3                         // ring depth: producer runs 2 tiles ahead
#define FULL_VEC 21                    // 21 full-wave 16B DMA instrs per tile
#define TAIL_LANES 16                  // +1 DMA instr with 16 active lanes
#define VM_PER_TILE 22                 // vmcnt events per staged tile
#define TILES_PER_BLOCK 13
#define THREADS 128                    // wave0 = producer, wave1 = consumer

#define GLOBAL_AS __attribute__((address_space(1)))
#define LDS_AS __attribute__((address_space(3)))

// gfx9 s_waitcnt imm: vmcnt[3:0]=bits[3:0], vmcnt[5:4]=bits[15:14],
// expcnt=bits[6:4] (=7, unconstrained), lgkmcnt=bits[11:8] (=15, unconstrained)
#define WAITCNT_VM(n) (((n) & 0xF) | (((n) >> 4) << 14) | (0x7 << 4) | (0xF << 8))

// Producer/consumer wave specialization. vmcnt is PER-WAVE: R6 failed because
// one wave held both the LDS-DMA and the ds_reads, and the compiler's alias-
// conservative waitcnt pass drained the prefetch before every compute phase.
// Here wave 0 only issues global_load_lds (zero VGPR data footprint) with
// manual s_waitcnt vmcnt(N) + raw s_barrier; wave 1 only does ds_read+VALU+
// stores (no LDS-DMA in its stream -> no spurious waits). Ring of 3 buffers:
// producer stays 2 tiles (44 KB) in flight at ~100% duty; 2 blocks/CU ->
// ~88 KB/CU sustained, vs R3's ~75 KB at 50% duty.
//
// Barrier protocol (both waves execute exactly nt barriers):
//   barrier(i) means: tile i's DMA has been vmcnt-retired (LDS visible).
//   producer after barrier(i): issue tile i+2 into buf (i+2)%3 (consumer
//   finished tile i-1 == buf (i+2)%3 before barrier(i)); wait vmcnt so only
//   tile i+2's 22 events remain -> tile i+1 arrived; barrier(i+1).
//   consumer after barrier(i): compute tile i from buf i%3.
//
// LDS row stride 85: bank(lane*85+j) = (lane*21+j)%32, 21 odd -> permutation
// over lanes per j -> 2 lanes/bank -> conflict-free (free per m136).
__global__ __launch_bounds__(THREADS) void yolo_post_kernel(
    const float* __restrict__ in, float* __restrict__ out, long long nrows) {
  __shared__ __align__(16) float tile[NBUF][TILE_F];

  const int wave = threadIdx.x >> 6;
  const int lane = threadIdx.x & 63;

  const long long full_tiles = nrows / ROWS_PER_TILE;
  long long t0 = (long long)blockIdx.x * TILES_PER_BLOCK;
  long long t1 = t0 + TILES_PER_BLOCK;
  if (t1 > full_tiles) t1 = full_tiles;
  const int nt = (int)(t1 > t0 ? t1 - t0 : 0);

  if (nt > 0) {
    if (wave == 0) {
      // ---------------- producer ----------------
      auto stage = [&](int b, long long tt) {
        const float* src = in + tt * TILE_F;
#pragma unroll
        for (int k = 0; k < FULL_VEC; ++k) {
          __builtin_amdgcn_global_load_lds(
              (const GLOBAL_AS void*)(src + (long long)(lane + k * 64) * 4),
              (LDS_AS void*)(&tile[b][k * 256]), 16, 0, 0);
        }
        if (lane < TAIL_LANES) {
          __builtin_amdgcn_global_load_lds(
              (const GLOBAL_AS void*)(src + (long long)(lane + FULL_VEC * 64) * 4),
              (LDS_AS void*)(&tile[b][FULL_VEC * 256]), 16, 0, 0);
        }
      };

      stage(0, t0);
      if (nt > 1) {
        stage(1, t0 + 1);
        __builtin_amdgcn_s_waitcnt(WAITCNT_VM(VM_PER_TILE));  // T0 arrived
      } else {
        __builtin_amdgcn_s_waitcnt(WAITCNT_VM(0));
      }
      __builtin_amdgcn_s_barrier();                           // barrier(0)
      for (int i = 0; i < nt; ++i) {
        if (i + 2 < nt) stage((int)((i + 2) % NBUF), t0 + i + 2);
        if (i + 1 < nt) {
          if (i + 2 < nt)
            __builtin_amdgcn_s_waitcnt(WAITCNT_VM(VM_PER_TILE)); // T(i+1) in
          else
            __builtin_amdgcn_s_waitcnt(WAITCNT_VM(0));
          __builtin_amdgcn_s_barrier();                       // barrier(i+1)
        }
      }
    } else {
      // ---------------- consumer ----------------
      __builtin_amdgcn_s_barrier();                           // barrier(0)
      for (int i = 0; i < nt; ++i) {
        const long long tt = t0 + i;
        const long long r = tt * ROWS_PER_TILE + lane;
        const float* row = &tile[i % NBUF][lane * ROW_F];

        float cx = row[0];
        float cy = row[1];
        float hw = row[2] * 0.5f;
        float hh = row[3] * 0.5f;
        float conf = row[4];
        float best = row[5];
        int bidx = 0;
#pragma unroll
        for (int c = 1; c < NCLS; ++c) {
          float x = row[5 + c];
          bool g = x > best;           // strict > keeps FIRST max (jnp.argmax)
          best = g ? x : best;
          bidx = g ? c : bidx;
        }
        float score = conf * best;
        bool keep = score > CONF_THRESH;
        float2 o01 = keep ? make_float2(cx - hw, cy - hh) : make_float2(0.f, 0.f);
        float2 o23 = keep ? make_float2(cx + hw, cy + hh) : make_float2(0.f, 0.f);
        float2 o45 = keep ? make_float2(score, (float)bidx) : make_float2(0.f, 0.f);
        float2* op = (float2*)(out + r * 6);   // r*24 B, 8 B aligned
        op[0] = o01;
        op[1] = o23;
        op[2] = o45;

        if (i + 1 < nt) __builtin_amdgcn_s_barrier();
      }
    }
  }

  // ---- partial tile (nrows % 64 != 0): block 0, consumer wave, direct global.
  // Empty for nrows = 403200. No barriers on this path.
  if (blockIdx.x == 0 && wave == 1) {
    const long long r = full_tiles * ROWS_PER_TILE + lane;
    if (r < nrows) {
      const float* __restrict__ row = in + r * ROW_F;
      float cx = row[0];
      float cy = row[1];
      float hw = row[2] * 0.5f;
      float hh = row[3] * 0.5f;
      float conf = row[4];
      float best = row[5];
      int bidx = 0;
      for (int c = 1; c < NCLS; ++c) {
        float x = row[5 + c];
        bool g = x > best;
        best = g ? x : best;
        bidx = g ? c : bidx;
      }
      float score = conf * best;
      bool keep = score > CONF_THRESH;
      float* op = out + r * 6;
      op[0] = keep ? cx - hw : 0.0f;
      op[1] = keep ? cy - hh : 0.0f;
      op[2] = keep ? cx + hw : 0.0f;
      op[3] = keep ? cy + hh : 0.0f;
      op[4] = keep ? score : 0.0f;
      op[5] = keep ? (float)bidx : 0.0f;
    }
  }
}

extern "C" void kernel_launch(void* const* d_in, const int* in_sizes, int n_in,
                              void* d_out, int out_size, void* d_ws, size_t ws_size,
                              hipStream_t stream) {
  const float* in = (const float*)d_in[0];
  float* out = (float*)d_out;
  const long long nrows = (long long)in_sizes[0] / ROW_F;      // 403200
  const long long full_tiles = nrows / ROWS_PER_TILE;          // 6300
  long long grid = (full_tiles + TILES_PER_BLOCK - 1) / TILES_PER_BLOCK;  // 485
  if (grid < 1) grid = 1;
  yolo_post_kernel<<<(int)grid, THREADS, 0, stream>>>(in, out, nrows);
}